// Round 1
// 341.621 us; speedup vs baseline: 1.1081x; 1.1081x over previous
//
#include <hip/hip_runtime.h>
#include <cstdint>
#include <cstddef>

typedef __bf16 bf16x8 __attribute__((ext_vector_type(8)));
typedef float f32x4 __attribute__((ext_vector_type(4)));
typedef unsigned short u16x8 __attribute__((ext_vector_type(8)));
typedef unsigned short u16x4 __attribute__((ext_vector_type(4)));
typedef short s16x4 __attribute__((ext_vector_type(4)));
typedef unsigned short u16;

#define L_SEQ 2048
#define D_HALF 1024
#define HDIM 64
// exp(s * SM_SCALE) = exp2(s * SM_SCALE * log2(e)); v_exp_f32 is base-2.
static constexpr float EXP2_SCALE = 0.12751742552639395f; // (1/sqrt(128))*log2(e)

__device__ inline u16 f2b(float f) {
  uint32_t u; __builtin_memcpy(&u, &f, 4);
  u = u + 0x7FFFu + ((u >> 16) & 1u);   // RNE
  return (u16)(u >> 16);
}

// single-instruction f32x2 -> packed bf16 (RNE); no builtin on gfx950.
__device__ inline uint32_t cvt_pk_bf16(float lo, float hi) {
  uint32_t r;
  asm("v_cvt_pk_bf16_f32 %0, %1, %2" : "=v"(r) : "v"(lo), "v"(hi));
  return r;
}

// ---------------------------------------------------------------------------
// f32 -> bf16 converters.
// ---------------------------------------------------------------------------
__global__ __launch_bounds__(256)
void convx(const float* xa, const float* xb, u16* dst) {
  const float* s = blockIdx.y ? xb : xa;
  size_t i = ((size_t)blockIdx.x * 256 + threadIdx.x) * 8;
  float4 v0 = *(const float4*)(s + i);
  float4 v1 = *(const float4*)(s + i + 4);
  u16x8 p;
  p[0] = f2b(v0.x); p[1] = f2b(v0.y); p[2] = f2b(v0.z); p[3] = f2b(v0.w);
  p[4] = f2b(v1.x); p[5] = f2b(v1.y); p[6] = f2b(v1.z); p[7] = f2b(v1.w);
  *(u16x8*)&dst[(size_t)blockIdx.y * 4194304 + i] = p;
}

struct CArg8 { const float* src[8]; };
__global__ __launch_bounds__(256)
void convw8(CArg8 a, u16* dst) {
  const int z = blockIdx.y;
  const float* s = a.src[z];
  size_t i = ((size_t)blockIdx.x * 256 + threadIdx.x) * 8;
  float4 v0 = *(const float4*)(s + i);
  float4 v1 = *(const float4*)(s + i + 4);
  u16x8 p;
  p[0] = f2b(v0.x); p[1] = f2b(v0.y); p[2] = f2b(v0.z); p[3] = f2b(v0.w);
  p[4] = f2b(v1.x); p[5] = f2b(v1.y); p[6] = f2b(v1.z); p[7] = f2b(v1.w);
  *(u16x8*)&dst[(size_t)z * 1048576 + i] = p;
}

// ---------------------------------------------------------------------------
// Batched GEMM: C[m][n] = sum_k A[m][k] * W[n][k]  (torch-Linear x@W.T form).
// All-bf16 inputs (x/o and W pre-converted). Register-prefetch pipeline:
// next K-tile's global loads issue between the two barriers -> latency
// overlaps the current tile's MFMA. LDS rows padded 64->72 u16 (b128 reads
// at the 8-deep structural floor). RESID: + f32 residual -> f32 z. vt:
// transposed epilogue to vT[b][h*64+d][t].
// ---------------------------------------------------------------------------
struct GArg { const u16* A; const u16* W; u16* C; const float* R; float* Z; int vt; };
struct GArgs { GArg g[6]; };

template <bool RESID>
__global__ __launch_bounds__(256, 2)
void gemm_nt(GArgs args, int M, int N, int K) {
  GArg ga = args.g[blockIdx.z];
  __shared__ __attribute__((aligned(16))) u16 As[128][72];
  __shared__ __attribute__((aligned(16))) u16 Bs[128][72];

  const int tid = threadIdx.x;
  const int wv = tid >> 6, lane = tid & 63;
  const int lane15 = lane & 15, quad = lane >> 4;
  const int m0 = blockIdx.y * 128, n0 = blockIdx.x * 128;
  const int wm = (wv >> 1) * 64, wn = (wv & 1) * 64;

  int rr[4], cc[4];
#pragma unroll
  for (int i = 0; i < 4; i++) { int c = tid + i * 256; rr[i] = c >> 3; cc[i] = (c & 7) * 8; }

  u16x8 ra[4], rb[4];
#pragma unroll
  for (int i = 0; i < 4; i++) {
    ra[i] = *(const u16x8*)&ga.A[(size_t)(m0 + rr[i]) * K + cc[i]];
    rb[i] = *(const u16x8*)&ga.W[(size_t)(n0 + rr[i]) * K + cc[i]];
  }

  f32x4 acc[4][4] = {};

  for (int k0 = 0; k0 < K; k0 += 64) {
    __syncthreads();
#pragma unroll
    for (int i = 0; i < 4; i++) {
      *(u16x8*)&As[rr[i]][cc[i]] = ra[i];
      *(u16x8*)&Bs[rr[i]][cc[i]] = rb[i];
    }
    if (k0 + 64 < K) {
#pragma unroll
      for (int i = 0; i < 4; i++) {
        ra[i] = *(const u16x8*)&ga.A[(size_t)(m0 + rr[i]) * K + k0 + 64 + cc[i]];
        rb[i] = *(const u16x8*)&ga.W[(size_t)(n0 + rr[i]) * K + k0 + 64 + cc[i]];
      }
    }
    __syncthreads();
#pragma unroll
    for (int kk = 0; kk < 64; kk += 32) {
      bf16x8 af[4], bw[4];
#pragma unroll
      for (int i = 0; i < 4; i++)
        af[i] = *(const bf16x8*)&As[wm + i * 16 + lane15][kk + quad * 8];
#pragma unroll
      for (int j = 0; j < 4; j++)
        bw[j] = *(const bf16x8*)&Bs[wn + j * 16 + lane15][kk + quad * 8];
#pragma unroll
      for (int i = 0; i < 4; i++)
#pragma unroll
        for (int j = 0; j < 4; j++)
          acc[i][j] = __builtin_amdgcn_mfma_f32_16x16x32_bf16(af[i], bw[j], acc[i][j], 0, 0, 0);
    }
  }

  if (!RESID && ga.vt) {
    // transposed epilogue: vT[b][gn][t], 4 consecutive tokens per u16x4
#pragma unroll
    for (int i = 0; i < 4; i++)
#pragma unroll
      for (int j = 0; j < 4; j++) {
        int gm0 = m0 + wm + i * 16 + quad * 4;       // token base (mult of 4)
        int gn  = n0 + wn + j * 16 + lane15;         // feature = h*64+d
        int bb = gm0 >> 11, t = gm0 & 2047;
        u16x4 pk;
#pragma unroll
        for (int r = 0; r < 4; r++) pk[r] = f2b(acc[i][j][r]);
        *(u16x4*)&ga.C[(size_t)bb * 2097152 + (size_t)gn * 2048 + t] = pk;
      }
  } else {
#pragma unroll
    for (int i = 0; i < 4; i++)
#pragma unroll
      for (int j = 0; j < 4; j++)
#pragma unroll
        for (int r = 0; r < 4; r++) {
          int gm = m0 + wm + i * 16 + quad * 4 + r;  // C/D: row=quad*4+reg
          int gn = n0 + wn + j * 16 + lane15;        //      col=lane&15
          size_t idx = (size_t)gm * N + gn;
          if (RESID) ga.Z[idx] = acc[i][j][r] + ga.R[idx];
          else       ga.C[idx] = f2b(acc[i][j][r]);
        }
  }
}

// ---------------------------------------------------------------------------
// Cross flash-attention, no-max softmax. Restructured this round:
//  * 32 q-rows per wave (2 Q fragments) -> K/V LDS reads amortized 2x.
//  * SWAPPED QK^T: mfma(K_frag, Q_frag) = S^T, so each lane holds a full
//    16-key slice of P for ONE q-row (key = 16*nt + 4*quad + r, q = lane15).
//  * PV via mfma_f32_16x16x16bf16_1k: its A-fragment layout (k = quad*4+j)
//    matches the swapped C-layout exactly -> P never touches LDS. Pack with
//    v_cvt_pk_bf16_f32 (2 vals/instr) straight into the A operand.
//    V consumed via ds_read_b64 from the transposed Vt tile (2-way bank
//    aliasing = free on CDNA4).
//  * Row-sum l: lane-local accumulate, one xor16+xor32 shuffle reduce at
//    the end, then a bpermute to redistribute 1/l to the C-layout rows.
// LDS bytes per (q-row x key-tile) drop ~2.4x vs the previous version; the
// f2b + ds_write_b16 relayout storm is gone entirely.
// ---------------------------------------------------------------------------
#if __has_builtin(__builtin_amdgcn_mfma_f32_16x16x16bf16_1k)
#define HAVE_MFMA16 1
#else
#define HAVE_MFMA16 0
#endif

__global__ __launch_bounds__(256, 2)
void attn_kernel(const u16* q_a, const u16* k_a, const u16* vt_a,
                 const u16* q_b, const u16* k_b, const u16* vt_b,
                 u16* o_a, u16* o_b) {
  const int br = blockIdx.z;
  const u16* Q  = br ? q_b : q_a;
  const u16* Kp = br ? k_a : k_b;
  const u16* Vp = br ? vt_a : vt_b;
  u16* O = br ? o_b : o_a;
  const int bh = blockIdx.y;
  const int b = bh >> 4, h = bh & 15;
  const int q0 = blockIdx.x * 128;

  const int tid = threadIdx.x, wv = tid >> 6, lane = tid & 63;
  const int lane15 = lane & 15, quad = lane >> 4;

  __shared__ __attribute__((aligned(16))) u16 Ks[2][64][72];
  __shared__ __attribute__((aligned(16))) u16 Vt[2][64][72];   // Vt[d][key]
#if !HAVE_MFMA16
  __shared__ __attribute__((aligned(16))) u16 Pw[4][2][16][72];
#endif

  const size_t base   = ((size_t)b * L_SEQ) * D_HALF + (size_t)h * HDIM;
  const size_t vbase  = (size_t)b * 2097152 + (size_t)(h * 64) * 2048;

  // staging slots: thread covers 2 u16x8 chunks of each 64x64 tile
  const int c1 = tid + 256;
  const int r0 = tid >> 3, cb0 = (tid & 7) * 8;
  const int r1 = c1 >> 3,  cb1 = (c1 & 7) * 8;

  // two q fragments per wave: rows q0 + wv*32 + f*16 + lane15
  bf16x8 qf[2][2];
#pragma unroll
  for (int f = 0; f < 2; f++) {
    const int qrow = q0 + wv * 32 + f * 16 + lane15;
#pragma unroll
    for (int c = 0; c < 2; c++)
      qf[f][c] = *(const bf16x8*)&Q[base + (size_t)qrow * D_HALF + c * 32 + quad * 8];
  }

  // stage tile 0
  u16x8 kr0 = *(const u16x8*)&Kp[base + (size_t)r0 * D_HALF + cb0];
  u16x8 kr1 = *(const u16x8*)&Kp[base + (size_t)r1 * D_HALF + cb1];
  u16x8 vr0 = *(const u16x8*)&Vp[vbase + (size_t)r0 * 2048 + cb0];
  u16x8 vr1 = *(const u16x8*)&Vp[vbase + (size_t)r1 * 2048 + cb1];
  *(u16x8*)&Ks[0][r0][cb0] = kr0;
  *(u16x8*)&Ks[0][r1][cb1] = kr1;
  *(u16x8*)&Vt[0][r0][cb0] = vr0;
  *(u16x8*)&Vt[0][r1][cb1] = vr1;
  __syncthreads();

  f32x4 oacc[2][4] = {};
  float lsum[2] = {0.f, 0.f};

  for (int it = 0; it < 32; it++) {
    const int cur = it & 1, nxt = cur ^ 1;
    if (it < 31) {
      const int kt = (it + 1) * 64;
      kr0 = *(const u16x8*)&Kp[base + (size_t)(kt + r0) * D_HALF + cb0];
      kr1 = *(const u16x8*)&Kp[base + (size_t)(kt + r1) * D_HALF + cb1];
      vr0 = *(const u16x8*)&Vp[vbase + (size_t)r0 * 2048 + kt + cb0];
      vr1 = *(const u16x8*)&Vp[vbase + (size_t)r1 * 2048 + kt + cb1];
    }

    // S^T = K Q^T  (swapped operands: A = K rows, B = Q^T).
    // s[f][nt][r] = S[q = lane15][key = nt*16 + quad*4 + r]
    f32x4 s[2][4];
#pragma unroll
    for (int nt = 0; nt < 4; nt++) {
      bf16x8 kb0 = *(const bf16x8*)&Ks[cur][nt * 16 + lane15][quad * 8];
      bf16x8 kb1 = *(const bf16x8*)&Ks[cur][nt * 16 + lane15][32 + quad * 8];
#pragma unroll
      for (int f = 0; f < 2; f++) {
        f32x4 a0 = {};
        a0 = __builtin_amdgcn_mfma_f32_16x16x32_bf16(kb0, qf[f][0], a0, 0, 0, 0);
        a0 = __builtin_amdgcn_mfma_f32_16x16x32_bf16(kb1, qf[f][1], a0, 0, 0, 0);
        s[f][nt] = a0;
      }
    }

    // p = exp2(S*c); keys are lane-local -> lane-local partial row sum;
    // pack pairs to bf16: pa[f][nt] IS the 16x16x16 A-fragment (k=quad*4+j).
    s16x4 pa[2][4];
#pragma unroll
    for (int f = 0; f < 2; f++)
#pragma unroll
      for (int nt = 0; nt < 4; nt++) {
        float p0 = __builtin_amdgcn_exp2f(s[f][nt][0] * EXP2_SCALE);
        float p1 = __builtin_amdgcn_exp2f(s[f][nt][1] * EXP2_SCALE);
        float p2 = __builtin_amdgcn_exp2f(s[f][nt][2] * EXP2_SCALE);
        float p3 = __builtin_amdgcn_exp2f(s[f][nt][3] * EXP2_SCALE);
        lsum[f] += (p0 + p1) + (p2 + p3);
        union { uint32_t u[2]; s16x4 v; } cv;
        cv.u[0] = cvt_pk_bf16(p0, p1);
        cv.u[1] = cvt_pk_bf16(p2, p3);
        pa[f][nt] = cv.v;
      }

#if HAVE_MFMA16
    // O += P V, K=16 chunks; B-frag: V[16nt+quad*4+j][dt*16+lane15] via b64.
#pragma unroll
    for (int dt = 0; dt < 4; dt++) {
      s16x4 bv[4];
#pragma unroll
      for (int nt = 0; nt < 4; nt++)
        bv[nt] = *(const s16x4*)&Vt[cur][dt * 16 + lane15][nt * 16 + quad * 4];
#pragma unroll
      for (int f = 0; f < 2; f++) {
        f32x4 t = oacc[f][dt];
#pragma unroll
        for (int nt = 0; nt < 4; nt++)
          t = __builtin_amdgcn_mfma_f32_16x16x16bf16_1k(pa[f][nt], bv[nt], t, 0, 0, 0);
        oacc[f][dt] = t;
      }
    }
#else
    // fallback: LDS relayout to 16x16x32 A-frags (per-wave buffer, in-order
    // DS + lgkmcnt drain).
#pragma unroll
    for (int f = 0; f < 2; f++)
#pragma unroll
      for (int nt = 0; nt < 4; nt++)
        *(s16x4*)&Pw[wv][f][lane15][nt * 16 + quad * 4] = pa[f][nt];
    __asm__ volatile("s_waitcnt lgkmcnt(0)" ::: "memory");
    bf16x8 pb[2][2];
#pragma unroll
    for (int f = 0; f < 2; f++) {
      pb[f][0] = *(const bf16x8*)&Pw[wv][f][lane15][quad * 8];
      pb[f][1] = *(const bf16x8*)&Pw[wv][f][lane15][32 + quad * 8];
    }
#pragma unroll
    for (int dt = 0; dt < 4; dt++) {
      bf16x8 bv0 = *(const bf16x8*)&Vt[cur][dt * 16 + lane15][quad * 8];
      bf16x8 bv1 = *(const bf16x8*)&Vt[cur][dt * 16 + lane15][32 + quad * 8];
#pragma unroll
      for (int f = 0; f < 2; f++) {
        f32x4 t = oacc[f][dt];
        t = __builtin_amdgcn_mfma_f32_16x16x32_bf16(pb[f][0], bv0, t, 0, 0, 0);
        t = __builtin_amdgcn_mfma_f32_16x16x32_bf16(pb[f][1], bv1, t, 0, 0, 0);
        oacc[f][dt] = t;
      }
    }
    __asm__ volatile("" ::: "memory");
#endif

    if (it < 31) {
      *(u16x8*)&Ks[nxt][r0][cb0] = kr0;
      *(u16x8*)&Ks[nxt][r1][cb1] = kr1;
      *(u16x8*)&Vt[nxt][r0][cb0] = vr0;
      *(u16x8*)&Vt[nxt][r1][cb1] = vr1;
    }
    __syncthreads();   // fences: nxt writes before next iter's reads; cur
                       // reads of this iter before iter+1 overwrites cur.
  }

  // finalize: lsum[f] holds this lane's partial for q = lane15; sum the 4
  // quads (xor16+xor32), then redistribute 1/l to C-layout rows (quad*4+r).
#pragma unroll
  for (int f = 0; f < 2; f++) {
    float lt = lsum[f];
    lt += __shfl_xor(lt, 16);
    lt += __shfl_xor(lt, 32);
    lsum[f] = lt;                    // every lane: total for q = lane15
  }
#pragma unroll
  for (int f = 0; f < 2; f++) {
    float linv[4];
#pragma unroll
    for (int r = 0; r < 4; r++)
      linv[r] = 1.0f / __shfl(lsum[f], quad * 4 + r);
#pragma unroll
    for (int dt = 0; dt < 4; dt++)
#pragma unroll
      for (int r = 0; r < 4; r++) {
        float val = oacc[f][dt][r] * linv[r];
        O[base + (size_t)(q0 + wv * 32 + f * 16 + quad * 4 + r) * D_HALF
          + dt * 16 + lane15] = f2b(val);
      }
  }
}

// ---------------------------------------------------------------------------
// LayerNorm over f32 z rows -> f32 out. One block per row.
// ---------------------------------------------------------------------------
__global__ __launch_bounds__(256)
void ln_kernel(const float* zA, const float* zB,
               const float* gA, const float* bA, const float* gB, const float* bB,
               float* out) {
  const int row = blockIdx.x, br = blockIdx.y;
  const float* z = (br ? zB : zA) + (size_t)row * D_HALF;
  const float* g  = br ? gB : gA;
  const float* be = br ? bB : bA;
  float* o = out + (size_t)br * ((size_t)4096 * D_HALF) + (size_t)row * D_HALF;

  float4 v = ((const float4*)z)[threadIdx.x];
  float s  = v.x + v.y + v.z + v.w;
  float s2 = v.x * v.x + v.y * v.y + v.z * v.z + v.w * v.w;
#pragma unroll
  for (int off = 32; off > 0; off >>= 1) {
    s  += __shfl_down(s, off);
    s2 += __shfl_down(s2, off);
  }
  __shared__ float red[8];
  int w = threadIdx.x >> 6, ln = threadIdx.x & 63;
  if (ln == 0) { red[w] = s; red[4 + w] = s2; }
  __syncthreads();
  if (threadIdx.x == 0) {
    red[0] = red[0] + red[1] + red[2] + red[3];
    red[4] = red[4] + red[5] + red[6] + red[7];
  }
  __syncthreads();
  float mu  = red[0] * (1.0f / 1024.0f);
  float var = red[4] * (1.0f / 1024.0f) - mu * mu;
  float rs  = rsqrtf(fmaxf(var, 0.0f) + 1e-5f);

  int col = threadIdx.x * 4;
  float4 gv = ((const float4*)g)[threadIdx.x];
  float4 bv = ((const float4*)be)[threadIdx.x];
  float4 ov;
  ov.x = (v.x - mu) * rs * gv.x + bv.x;
  ov.y = (v.y - mu) * rs * gv.y + bv.y;
  ov.z = (v.z - mu) * rs * gv.z + bv.z;
  ov.w = (v.w - mu) * rs * gv.w + bv.w;
  *(float4*)&o[col] = ov;
}

// ---------------------------------------------------------------------------
extern "C" void kernel_launch(void* const* d_in, const int* in_sizes, int n_in,
                              void* d_out, int out_size, void* d_ws, size_t ws_size,
                              hipStream_t stream) {
  const float* x_a     = (const float*)d_in[0];
  const float* x_b     = (const float*)d_in[1];
  const float* Wq_a    = (const float*)d_in[2];
  const float* Wq_b    = (const float*)d_in[3];
  const float* Wk_a    = (const float*)d_in[4];
  const float* Wk_b    = (const float*)d_in[5];
  const float* Wv_a    = (const float*)d_in[6];
  const float* Wv_b    = (const float*)d_in[7];
  const float* Wo_a    = (const float*)d_in[8];
  const float* Wo_b    = (const float*)d_in[9];
  const float* gamma_a = (const float*)d_in[10];
  const float* beta_a  = (const float*)d_in[11];
  const float* gamma_b = (const float*)d_in[12];
  const float* beta_b  = (const float*)d_in[13];

  // Workspace map (ws = 64 MB = 32M u16; BUF = 4M u16 = 8 MB):
  //   slots 0-5: q_a,k_a,vt_a,q_b,k_b,vt_b (QKV outputs, read by attn)
  //   ws+24M u16 (48 MB): 8 bf16 weights (Wq/Wk/Wv a,b = 12 MB; Wo a,b = 4 MB)
  //   phase 3: z_a/z_b f32 overwrite slots 0-3 (dead after attn)
  // d_out (32 MB) doubles as scratch:
  //   phase 1: xbf_a/xbf_b (16 MB) read by QKV GEMM
  //   phase 2: o_a/o_b (16 MB) written by attn, read by out-proj
  //   ln writes the final f32 output last.
  const size_t BUF = (size_t)4096 * 1024;
  u16* ws   = (u16*)d_ws;
  u16* q_a  = ws + 0 * BUF; u16* k_a  = ws + 1 * BUF; u16* vt_a = ws + 2 * BUF;
  u16* q_b  = ws + 3 * BUF; u16* k_b  = ws + 4 * BUF; u16* vt_b = ws + 5 * BUF;
  u16* wall = ws + 6 * BUF;                    // 8 x 1M-u16 bf16 weights
  float* z_a = (float*)(ws + 0 * BUF);
  float* z_b = (float*)(ws + 2 * BUF);

  u16* xbf_a = (u16*)d_out;
  u16* xbf_b = xbf_a + 4194304;
  u16* o_a   = (u16*)d_out;                    // reuses xbf region (dead)
  u16* o_b   = o_a + 4194304;

  const int M = 4096, N = 1024, K = 1024;

  convx<<<dim3(2048, 2), 256, 0, stream>>>(x_a, x_b, xbf_a);

  CArg8 cw;
  cw.src[0] = Wq_a; cw.src[1] = Wk_a; cw.src[2] = Wv_a;
  cw.src[3] = Wq_b; cw.src[4] = Wk_b; cw.src[5] = Wv_b;
  cw.src[6] = Wo_a; cw.src[7] = Wo_b;
  convw8<<<dim3(512, 8), 256, 0, stream>>>(cw, wall);

  GArgs qkv;
  qkv.g[0] = GArg{xbf_a, wall + 0 * 1048576, q_a,  nullptr, nullptr, 0};
  qkv.g[1] = GArg{xbf_a, wall + 1 * 1048576, k_a,  nullptr, nullptr, 0};
  qkv.g[2] = GArg{xbf_a, wall + 2 * 1048576, vt_a, nullptr, nullptr, 1};
  qkv.g[3] = GArg{xbf_b, wall + 3 * 1048576, q_b,  nullptr, nullptr, 0};
  qkv.g[4] = GArg{xbf_b, wall + 4 * 1048576, k_b,  nullptr, nullptr, 0};
  qkv.g[5] = GArg{xbf_b, wall + 5 * 1048576, vt_b, nullptr, nullptr, 1};
  gemm_nt<false><<<dim3(8, 32, 6), 256, 0, stream>>>(qkv, M, N, K);

  attn_kernel<<<dim3(16, 32, 2), 256, 0, stream>>>(q_a, k_a, vt_a, q_b, k_b, vt_b, o_a, o_b);

  GArgs op;
  op.g[0] = GArg{o_a, wall + 6 * 1048576, nullptr, x_a, z_a, 0};
  op.g[1] = GArg{o_b, wall + 7 * 1048576, nullptr, x_b, z_b, 0};
  op.g[2] = op.g[0]; op.g[3] = op.g[0]; op.g[4] = op.g[0]; op.g[5] = op.g[0];
  gemm_nt<true><<<dim3(8, 32, 2), 256, 0, stream>>>(op, M, N, K);

  ln_kernel<<<dim3(4096, 2), 256, 0, stream>>>(z_a, z_b, gamma_a, beta_a,
                                               gamma_b, beta_b, (float*)d_out);
}

// Round 2
// 340.344 us; speedup vs baseline: 1.1123x; 1.0038x over previous
//
#include <hip/hip_runtime.h>
#include <cstdint>
#include <cstddef>

typedef __bf16 bf16x8 __attribute__((ext_vector_type(8)));
typedef float f32x4 __attribute__((ext_vector_type(4)));
typedef unsigned short u16x8 __attribute__((ext_vector_type(8)));
typedef unsigned short u16x4 __attribute__((ext_vector_type(4)));
typedef short s16x4 __attribute__((ext_vector_type(4)));
typedef unsigned short u16;

#define L_SEQ 2048
#define D_HALF 1024
#define HDIM 64
// exp(s/sqrt(128)) = exp2(s * EXP2_SCALE); folded into the Q-projection
// epilogue (f32 multiply before the bf16 round -> precision-neutral).
static constexpr float EXP2_SCALE = 0.12751742552639395f; // (1/sqrt(128))*log2(e)

__device__ inline u16 f2b(float f) {
  uint32_t u; __builtin_memcpy(&u, &f, 4);
  u = u + 0x7FFFu + ((u >> 16) & 1u);   // RNE
  return (u16)(u >> 16);
}

// single-instruction f32x2 -> packed bf16 (RNE); no builtin on gfx950.
__device__ inline uint32_t cvt_pk_bf16(float lo, float hi) {
  uint32_t r;
  asm("v_cvt_pk_bf16_f32 %0, %1, %2" : "=v"(r) : "v"(lo), "v"(hi));
  return r;
}

// async global->LDS, 16B per lane; LDS dest is wave-uniform base + lane*16.
#define GLOAD16(gp, lp) __builtin_amdgcn_global_load_lds( \
    (const __attribute__((address_space(1))) unsigned int*)(gp), \
    (__attribute__((address_space(3))) unsigned int*)(lp), 16, 0, 0)

// ---------------------------------------------------------------------------
// f32 -> bf16 converters.
// ---------------------------------------------------------------------------
__global__ __launch_bounds__(256)
void convx(const float* xa, const float* xb, u16* dst) {
  const float* s = blockIdx.y ? xb : xa;
  size_t i = ((size_t)blockIdx.x * 256 + threadIdx.x) * 8;
  float4 v0 = *(const float4*)(s + i);
  float4 v1 = *(const float4*)(s + i + 4);
  u16x8 p;
  p[0] = f2b(v0.x); p[1] = f2b(v0.y); p[2] = f2b(v0.z); p[3] = f2b(v0.w);
  p[4] = f2b(v1.x); p[5] = f2b(v1.y); p[6] = f2b(v1.z); p[7] = f2b(v1.w);
  *(u16x8*)&dst[(size_t)blockIdx.y * 4194304 + i] = p;
}

struct CArg8 { const float* src[8]; };
__global__ __launch_bounds__(256)
void convw8(CArg8 a, u16* dst) {
  const int z = blockIdx.y;
  const float* s = a.src[z];
  size_t i = ((size_t)blockIdx.x * 256 + threadIdx.x) * 8;
  float4 v0 = *(const float4*)(s + i);
  float4 v1 = *(const float4*)(s + i + 4);
  u16x8 p;
  p[0] = f2b(v0.x); p[1] = f2b(v0.y); p[2] = f2b(v0.z); p[3] = f2b(v0.w);
  p[4] = f2b(v1.x); p[5] = f2b(v1.y); p[6] = f2b(v1.z); p[7] = f2b(v1.w);
  *(u16x8*)&dst[(size_t)z * 1048576 + i] = p;
}

// ---------------------------------------------------------------------------
// Batched GEMM: C[m][n] = sum_k A[m][k] * W[n][k]  (torch-Linear x@W.T form).
// This round: global_load_lds (width=16) staging into LINEAR double-buffered
// LDS [128][64], with the XOR chunk swizzle applied on the SOURCE address
// (rule 21: gload_lds writes linearly -> pre-swizzle global src) and the same
// XOR on the ds_read side. Row stride 128B == 0 mod 32 banks, so the swizzle
// is what makes the b128 frag reads 2-way (free). Barrier at loop TOP: the
// prefetch issued after it stays in flight across the whole compute phase
// (m97 structure, 874 TF class). alpha: folded scalar on the bf16 epilogue
// (softmax scale goes into Q here). RESID: + f32 residual -> f32 z. vt:
// transposed epilogue to vT[b][h*64+d][t].
// ---------------------------------------------------------------------------
struct GArg { const u16* A; const u16* W; u16* C; const float* R; float* Z;
              int vt; float alpha; };
struct GArgs { GArg g[6]; };

template <bool RESID>
__global__ __launch_bounds__(256, 2)
void gemm_nt(GArgs args, int M, int N, int K) {
  GArg ga = args.g[blockIdx.z];
  __shared__ __attribute__((aligned(16))) u16 As[2][8192];   // [128][64] linear
  __shared__ __attribute__((aligned(16))) u16 Bs[2][8192];

  const int tid = threadIdx.x;
  const int wv = tid >> 6, lane = tid & 63;
  const int lane15 = lane & 15, quad = lane >> 4;
  const int m0 = blockIdx.y * 128, n0 = blockIdx.x * 128;
  const int wm = (wv >> 1) * 64, wn = (wv & 1) * 64;

  // staging: wave issue j covers LDS rows wv*32+j*8 .. +7 (1KB linear).
  // lane -> row wv*32+j*8+(lane>>3), physical chunk lane&7. Source chunk is
  // XOR-swizzled so that the read-side XOR recovers logical order.
  const int srow = lane >> 3;
  const int scol = ((lane & 7) ^ srow) * 8;      // swizzled source u16 col

  const u16* pA[4]; const u16* pW[4]; int lo[4];
#pragma unroll
  for (int j = 0; j < 4; j++) {
    int r = wv * 32 + j * 8;
    pA[j] = ga.A + (size_t)(m0 + r + srow) * K + scol;
    pW[j] = ga.W + (size_t)(n0 + r + srow) * K + scol;
    lo[j] = r * 64;
  }

  f32x4 acc[4][4] = {};
  const int swz = (lane15 & 7) << 4;             // read-side XOR (bytes)

#pragma unroll
  for (int j = 0; j < 4; j++) {                  // prologue: stage buf 0
    GLOAD16(pA[j], &As[0][lo[j]]);
    GLOAD16(pW[j], &Bs[0][lo[j]]);
  }

  for (int k0 = 0; k0 < K; k0 += 64) {
    const int cur = (k0 >> 6) & 1;
    __syncthreads();     // drains vmcnt -> buf cur complete; prev reads done
    if (k0 + 64 < K) {
#pragma unroll
      for (int j = 0; j < 4; j++) {              // prefetch stays in flight
        GLOAD16(pA[j] + k0 + 64, &As[cur ^ 1][lo[j]]);
        GLOAD16(pW[j] + k0 + 64, &Bs[cur ^ 1][lo[j]]);
      }
    }
    const char* ab = (const char*)As[cur];
    const char* bb = (const char*)Bs[cur];
#pragma unroll
    for (int kk = 0; kk < 2; kk++) {
      const int cb = kk * 64 + quad * 16;
      bf16x8 af[4], bw[4];
#pragma unroll
      for (int i = 0; i < 4; i++)
        af[i] = *(const bf16x8*)(ab + (wm + i * 16 + lane15) * 128 + (cb ^ swz));
#pragma unroll
      for (int j = 0; j < 4; j++)
        bw[j] = *(const bf16x8*)(bb + (wn + j * 16 + lane15) * 128 + (cb ^ swz));
#pragma unroll
      for (int i = 0; i < 4; i++)
#pragma unroll
        for (int j = 0; j < 4; j++)
          acc[i][j] = __builtin_amdgcn_mfma_f32_16x16x32_bf16(af[i], bw[j], acc[i][j], 0, 0, 0);
    }
  }

  const float al = ga.alpha;
  if (!RESID && ga.vt) {
    // transposed epilogue: vT[b][gn][t], 4 consecutive tokens per u16x4
#pragma unroll
    for (int i = 0; i < 4; i++)
#pragma unroll
      for (int j = 0; j < 4; j++) {
        int gm0 = m0 + wm + i * 16 + quad * 4;       // token base (mult of 4)
        int gn  = n0 + wn + j * 16 + lane15;         // feature = h*64+d
        int bb2 = gm0 >> 11, t = gm0 & 2047;
        u16x4 pk;
#pragma unroll
        for (int r = 0; r < 4; r++) pk[r] = f2b(acc[i][j][r] * al);
        *(u16x4*)&ga.C[(size_t)bb2 * 2097152 + (size_t)gn * 2048 + t] = pk;
      }
  } else {
#pragma unroll
    for (int i = 0; i < 4; i++)
#pragma unroll
      for (int j = 0; j < 4; j++)
#pragma unroll
        for (int r = 0; r < 4; r++) {
          int gm = m0 + wm + i * 16 + quad * 4 + r;  // C/D: row=quad*4+reg
          int gn = n0 + wn + j * 16 + lane15;        //      col=lane&15
          size_t idx = (size_t)gm * N + gn;
          if (RESID) ga.Z[idx] = acc[i][j][r] + ga.R[idx];
          else       ga.C[idx] = f2b(acc[i][j][r] * al);
        }
  }
}

// ---------------------------------------------------------------------------
// Cross flash-attention, no-max softmax. This round:
//  * K/V LDS: unpadded [64][64] with XOR swizzle (byte ^= (row&7)<<4).
//    Row stride 128B == 0 mod 32 banks; with the swizzle every access
//    pattern here (b128 K-frag read, b64 V-frag read, b128 staging write)
//    is 2-way per 16-lane phase = free. Was [64][72] padded, 1.26e7
//    conflict cycles/dispatch. Also 36->32 KB -> +1 resident block.
//  * softmax scale pre-folded into Q by the QKV GEMM epilogue -> the
//    per-element VALU mul is gone; p = exp2(s) directly.
//  * s_setprio(1) around MFMA clusters (T5).
// Structure retained from last round: 32 q-rows/wave, swapped QK^T
// (mfma(K,Q) = S^T -> P lane-local), PV via mfma_f32_16x16x16bf16_1k whose
// A-frag layout (k=quad*4+j) matches the swapped C-layout, so P never
// touches LDS (cvt_pk straight into the A operand).
// ---------------------------------------------------------------------------
#define SWZ(row, bcol) ((row) * 128 + ((bcol) ^ (((row) & 7) << 4)))

__global__ __launch_bounds__(256, 2)
void attn_kernel(const u16* q_a, const u16* k_a, const u16* vt_a,
                 const u16* q_b, const u16* k_b, const u16* vt_b,
                 u16* o_a, u16* o_b) {
  const int br = blockIdx.z;
  const u16* Q  = br ? q_b : q_a;
  const u16* Kp = br ? k_a : k_b;
  const u16* Vp = br ? vt_a : vt_b;
  u16* O = br ? o_b : o_a;
  const int bh = blockIdx.y;
  const int b = bh >> 4, h = bh & 15;
  const int q0 = blockIdx.x * 128;

  const int tid = threadIdx.x, wv = tid >> 6, lane = tid & 63;
  const int lane15 = lane & 15, quad = lane >> 4;

  __shared__ __attribute__((aligned(16))) u16 Ks[2][4096];   // [64][64] swz
  __shared__ __attribute__((aligned(16))) u16 Vt[2][4096];   // [d][key] swz

  const size_t base   = ((size_t)b * L_SEQ) * D_HALF + (size_t)h * HDIM;
  const size_t vbase  = (size_t)b * 2097152 + (size_t)(h * 64) * 2048;

  // staging slots: thread covers 2 u16x8 chunks of each 64x64 tile
  const int c1 = tid + 256;
  const int r0 = tid >> 3, cb0 = (tid & 7) * 16;   // byte col
  const int r1 = c1 >> 3,  cb1 = (c1 & 7) * 16;
  const int wo0 = SWZ(r0, cb0), wo1 = SWZ(r1, cb1);

  // two q fragments per wave: rows q0 + wv*32 + f*16 + lane15
  bf16x8 qf[2][2];
#pragma unroll
  for (int f = 0; f < 2; f++) {
    const int qrow = q0 + wv * 32 + f * 16 + lane15;
#pragma unroll
    for (int c = 0; c < 2; c++)
      qf[f][c] = *(const bf16x8*)&Q[base + (size_t)qrow * D_HALF + c * 32 + quad * 8];
  }

  // stage tile 0
  u16x8 kr0 = *(const u16x8*)&Kp[base + (size_t)r0 * D_HALF + cb0 / 2];
  u16x8 kr1 = *(const u16x8*)&Kp[base + (size_t)r1 * D_HALF + cb1 / 2];
  u16x8 vr0 = *(const u16x8*)&Vp[vbase + (size_t)r0 * 2048 + cb0 / 2];
  u16x8 vr1 = *(const u16x8*)&Vp[vbase + (size_t)r1 * 2048 + cb1 / 2];
  *(u16x8*)((char*)Ks[0] + wo0) = kr0;
  *(u16x8*)((char*)Ks[0] + wo1) = kr1;
  *(u16x8*)((char*)Vt[0] + wo0) = vr0;
  *(u16x8*)((char*)Vt[0] + wo1) = vr1;
  __syncthreads();

  f32x4 oacc[2][4] = {};
  float lsum[2] = {0.f, 0.f};
  const int aswz = (lane15 & 7) << 4;

  for (int it = 0; it < 32; it++) {
    const int cur = it & 1, nxt = cur ^ 1;
    if (it < 31) {
      const int kt = (it + 1) * 64;
      kr0 = *(const u16x8*)&Kp[base + (size_t)(kt + r0) * D_HALF + cb0 / 2];
      kr1 = *(const u16x8*)&Kp[base + (size_t)(kt + r1) * D_HALF + cb1 / 2];
      vr0 = *(const u16x8*)&Vp[vbase + (size_t)r0 * 2048 + kt + cb0 / 2];
      vr1 = *(const u16x8*)&Vp[vbase + (size_t)r1 * 2048 + kt + cb1 / 2];
    }

    const char* kb = (const char*)Ks[cur];
    const char* vb = (const char*)Vt[cur];

    // S^T = K Q^T  (swapped operands: A = K rows, B = Q^T).
    // s[f][nt][r] = S[q = lane15][key = nt*16 + quad*4 + r]
    f32x4 s[2][4];
    __builtin_amdgcn_s_setprio(1);
#pragma unroll
    for (int nt = 0; nt < 4; nt++) {
      const int krow = nt * 16 + lane15;
      bf16x8 kb0 = *(const bf16x8*)(kb + SWZ(krow, quad * 16));
      bf16x8 kb1 = *(const bf16x8*)(kb + SWZ(krow, 64 + quad * 16));
#pragma unroll
      for (int f = 0; f < 2; f++) {
        f32x4 a0 = {};
        a0 = __builtin_amdgcn_mfma_f32_16x16x32_bf16(kb0, qf[f][0], a0, 0, 0, 0);
        a0 = __builtin_amdgcn_mfma_f32_16x16x32_bf16(kb1, qf[f][1], a0, 0, 0, 0);
        s[f][nt] = a0;
      }
    }
    __builtin_amdgcn_s_setprio(0);

    // p = exp2(s)  (scale pre-folded into Q); keys lane-local -> lane-local
    // partial row sum; pack pairs: pa[f][nt] IS the 16x16x16 A-fragment.
    s16x4 pa[2][4];
#pragma unroll
    for (int f = 0; f < 2; f++)
#pragma unroll
      for (int nt = 0; nt < 4; nt++) {
        float p0 = __builtin_amdgcn_exp2f(s[f][nt][0]);
        float p1 = __builtin_amdgcn_exp2f(s[f][nt][1]);
        float p2 = __builtin_amdgcn_exp2f(s[f][nt][2]);
        float p3 = __builtin_amdgcn_exp2f(s[f][nt][3]);
        lsum[f] += (p0 + p1) + (p2 + p3);
        union { uint32_t u[2]; s16x4 v; } cv;
        cv.u[0] = cvt_pk_bf16(p0, p1);
        cv.u[1] = cvt_pk_bf16(p2, p3);
        pa[f][nt] = cv.v;
      }

    // O += P V, K=16 chunks; B-frag: V[16nt+quad*4+j][dt*16+lane15] via b64.
    __builtin_amdgcn_s_setprio(1);
#pragma unroll
    for (int dt = 0; dt < 4; dt++) {
      const int vrow = dt * 16 + lane15;
      s16x4 bv[4];
#pragma unroll
      for (int nt = 0; nt < 4; nt++)
        bv[nt] = *(const s16x4*)(vb + SWZ(vrow, nt * 32 + quad * 8));
#pragma unroll
      for (int f = 0; f < 2; f++) {
        f32x4 t = oacc[f][dt];
#pragma unroll
        for (int nt = 0; nt < 4; nt++)
          t = __builtin_amdgcn_mfma_f32_16x16x16bf16_1k(pa[f][nt], bv[nt], t, 0, 0, 0);
        oacc[f][dt] = t;
      }
    }
    __builtin_amdgcn_s_setprio(0);

    if (it < 31) {
      *(u16x8*)((char*)Ks[nxt] + wo0) = kr0;
      *(u16x8*)((char*)Ks[nxt] + wo1) = kr1;
      *(u16x8*)((char*)Vt[nxt] + wo0) = vr0;
      *(u16x8*)((char*)Vt[nxt] + wo1) = vr1;
    }
    __syncthreads();   // fences: nxt writes before next iter's reads; cur
                       // reads of this iter before iter+1 overwrites cur.
  }

  // finalize: lsum[f] holds this lane's partial for q = lane15; sum the 4
  // quads (xor16+xor32), then redistribute 1/l to C-layout rows (quad*4+r).
#pragma unroll
  for (int f = 0; f < 2; f++) {
    float lt = lsum[f];
    lt += __shfl_xor(lt, 16);
    lt += __shfl_xor(lt, 32);
    lsum[f] = lt;                    // every lane: total for q = lane15
  }
#pragma unroll
  for (int f = 0; f < 2; f++) {
    float linv[4];
#pragma unroll
    for (int r = 0; r < 4; r++)
      linv[r] = 1.0f / __shfl(lsum[f], quad * 4 + r);
#pragma unroll
    for (int dt = 0; dt < 4; dt++)
#pragma unroll
      for (int r = 0; r < 4; r++) {
        float val = oacc[f][dt][r] * linv[r];
        O[base + (size_t)(q0 + wv * 32 + f * 16 + quad * 4 + r) * D_HALF
          + dt * 16 + lane15] = f2b(val);
      }
  }
}

// ---------------------------------------------------------------------------
// LayerNorm over f32 z rows -> f32 out. One block per row.
// ---------------------------------------------------------------------------
__global__ __launch_bounds__(256)
void ln_kernel(const float* zA, const float* zB,
               const float* gA, const float* bA, const float* gB, const float* bB,
               float* out) {
  const int row = blockIdx.x, br = blockIdx.y;
  const float* z = (br ? zB : zA) + (size_t)row * D_HALF;
  const float* g  = br ? gB : gA;
  const float* be = br ? bB : bA;
  float* o = out + (size_t)br * ((size_t)4096 * D_HALF) + (size_t)row * D_HALF;

  float4 v = ((const float4*)z)[threadIdx.x];
  float s  = v.x + v.y + v.z + v.w;
  float s2 = v.x * v.x + v.y * v.y + v.z * v.z + v.w * v.w;
#pragma unroll
  for (int off = 32; off > 0; off >>= 1) {
    s  += __shfl_down(s, off);
    s2 += __shfl_down(s2, off);
  }
  __shared__ float red[8];
  int w = threadIdx.x >> 6, ln = threadIdx.x & 63;
  if (ln == 0) { red[w] = s; red[4 + w] = s2; }
  __syncthreads();
  if (threadIdx.x == 0) {
    red[0] = red[0] + red[1] + red[2] + red[3];
    red[4] = red[4] + red[5] + red[6] + red[7];
  }
  __syncthreads();
  float mu  = red[0] * (1.0f / 1024.0f);
  float var = red[4] * (1.0f / 1024.0f) - mu * mu;
  float rs  = rsqrtf(fmaxf(var, 0.0f) + 1e-5f);

  int col = threadIdx.x * 4;
  float4 gv = ((const float4*)g)[threadIdx.x];
  float4 bv = ((const float4*)be)[threadIdx.x];
  float4 ov;
  ov.x = (v.x - mu) * rs * gv.x + bv.x;
  ov.y = (v.y - mu) * rs * gv.y + bv.y;
  ov.z = (v.z - mu) * rs * gv.z + bv.z;
  ov.w = (v.w - mu) * rs * gv.w + bv.w;
  *(float4*)&o[col] = ov;
}

// ---------------------------------------------------------------------------
extern "C" void kernel_launch(void* const* d_in, const int* in_sizes, int n_in,
                              void* d_out, int out_size, void* d_ws, size_t ws_size,
                              hipStream_t stream) {
  const float* x_a     = (const float*)d_in[0];
  const float* x_b     = (const float*)d_in[1];
  const float* Wq_a    = (const float*)d_in[2];
  const float* Wq_b    = (const float*)d_in[3];
  const float* Wk_a    = (const float*)d_in[4];
  const float* Wk_b    = (const float*)d_in[5];
  const float* Wv_a    = (const float*)d_in[6];
  const float* Wv_b    = (const float*)d_in[7];
  const float* Wo_a    = (const float*)d_in[8];
  const float* Wo_b    = (const float*)d_in[9];
  const float* gamma_a = (const float*)d_in[10];
  const float* beta_a  = (const float*)d_in[11];
  const float* gamma_b = (const float*)d_in[12];
  const float* beta_b  = (const float*)d_in[13];

  // Workspace map (ws = 64 MB = 32M u16; BUF = 4M u16 = 8 MB):
  //   slots 0-5: q_a,k_a,vt_a,q_b,k_b,vt_b (QKV outputs, read by attn)
  //   ws+24M u16 (48 MB): 8 bf16 weights (Wq/Wk/Wv a,b = 12 MB; Wo a,b = 4 MB)
  //   phase 3: z_a/z_b f32 overwrite slots 0-3 (dead after attn)
  // d_out (32 MB) doubles as scratch:
  //   phase 1: xbf_a/xbf_b (16 MB) read by QKV GEMM
  //   phase 2: o_a/o_b (16 MB) written by attn, read by out-proj
  //   ln writes the final f32 output last.
  const size_t BUF = (size_t)4096 * 1024;
  u16* ws   = (u16*)d_ws;
  u16* q_a  = ws + 0 * BUF; u16* k_a  = ws + 1 * BUF; u16* vt_a = ws + 2 * BUF;
  u16* q_b  = ws + 3 * BUF; u16* k_b  = ws + 4 * BUF; u16* vt_b = ws + 5 * BUF;
  u16* wall = ws + 6 * BUF;                    // 8 x 1M-u16 bf16 weights
  float* z_a = (float*)(ws + 0 * BUF);
  float* z_b = (float*)(ws + 2 * BUF);

  u16* xbf_a = (u16*)d_out;
  u16* xbf_b = xbf_a + 4194304;
  u16* o_a   = (u16*)d_out;                    // reuses xbf region (dead)
  u16* o_b   = o_a + 4194304;

  const int M = 4096, N = 1024, K = 1024;

  convx<<<dim3(2048, 2), 256, 0, stream>>>(x_a, x_b, xbf_a);

  CArg8 cw;
  cw.src[0] = Wq_a; cw.src[1] = Wk_a; cw.src[2] = Wv_a;
  cw.src[3] = Wq_b; cw.src[4] = Wk_b; cw.src[5] = Wv_b;
  cw.src[6] = Wo_a; cw.src[7] = Wo_b;
  convw8<<<dim3(512, 8), 256, 0, stream>>>(cw, wall);

  GArgs qkv;
  qkv.g[0] = GArg{xbf_a, wall + 0 * 1048576, q_a,  nullptr, nullptr, 0, EXP2_SCALE};
  qkv.g[1] = GArg{xbf_a, wall + 1 * 1048576, k_a,  nullptr, nullptr, 0, 1.0f};
  qkv.g[2] = GArg{xbf_a, wall + 2 * 1048576, vt_a, nullptr, nullptr, 1, 1.0f};
  qkv.g[3] = GArg{xbf_b, wall + 3 * 1048576, q_b,  nullptr, nullptr, 0, EXP2_SCALE};
  qkv.g[4] = GArg{xbf_b, wall + 4 * 1048576, k_b,  nullptr, nullptr, 0, 1.0f};
  qkv.g[5] = GArg{xbf_b, wall + 5 * 1048576, vt_b, nullptr, nullptr, 1, 1.0f};
  gemm_nt<false><<<dim3(8, 32, 6), 256, 0, stream>>>(qkv, M, N, K);

  attn_kernel<<<dim3(16, 32, 2), 256, 0, stream>>>(q_a, k_a, vt_a, q_b, k_b, vt_b, o_a, o_b);

  GArgs op;
  op.g[0] = GArg{o_a, wall + 6 * 1048576, nullptr, x_a, z_a, 0, 1.0f};
  op.g[1] = GArg{o_b, wall + 7 * 1048576, nullptr, x_b, z_b, 0, 1.0f};
  op.g[2] = op.g[0]; op.g[3] = op.g[0]; op.g[4] = op.g[0]; op.g[5] = op.g[0];
  gemm_nt<true><<<dim3(8, 32, 2), 256, 0, stream>>>(op, M, N, K);

  ln_kernel<<<dim3(4096, 2), 256, 0, stream>>>(z_a, z_b, gamma_a, beta_a,
                                               gamma_b, beta_b, (float*)d_out);
}